// Round 1
// baseline (574.384 us; speedup 1.0000x reference)
//
#include <hip/hip_runtime.h>

// Problem constants (from reference): B=32, N=8192, C=512, K=128
#define PB 32
#define PN 8192
#define PC 512
#define PK 128

// Dtype model (validated R4): one_hot f32, id i32, d_out f32 (B*N ++ B*K).
//
// R5 post-mortem: fused single-kernel + fence/spin REGRESSED (575 -> 629 us):
// timed window is dominated by harness restore (2 GiB d_ws poison ~338 us +
// one_hot restore ~160 us). Our kernels are the residual ~65 us.
// R7 (this round): kernel A emits a per-wave __ballot bitmask (32 KB in d_ws)
// alongside the gather; kernel B compacts from the bitmask (1 KB/row) instead
// of re-reading out0 (1 MB) with 8 serialized LDS-scan phases.

// Kernel A: gather column `id`, 1 element per thread so each wave's 64 lanes
// cover 64 consecutive n -> __ballot(pred) IS the occupancy word for that
// 64-element span. 1024 blocks x 256 threads = exactly B*N threads,
// 16 waves/CU (4/SIMD) hiding the scattered-load latency.
__global__ __launch_bounds__(256) void gather_col(
    const float* __restrict__ one_hot,
    const int* __restrict__ id_ptr,
    float* __restrict__ out0,
    unsigned long long* __restrict__ masks)   // B*N/64 = 4096 words in d_ws
{
    const int t  = blockIdx.x * 256 + threadIdx.x;   // 0 .. B*N-1
    const int id = id_ptr[0];

    float v = __builtin_nontemporal_load(one_hot + (size_t)t * PC + (size_t)id);
    __builtin_nontemporal_store(v, out0 + t);

    const unsigned long long m = __ballot(v != 0.0f);
    if ((threadIdx.x & 63) == 0)
        masks[t >> 6] = m;   // word (b*128 + n/64); bit l <-> n = word*64 + l
}

// Kernel B: per-row stable compaction from the bitmask. One block of 128
// threads per batch row; thread i owns occupancy word i (64 n's). popcount ->
// shfl-based exclusive scan across 128 threads -> each thread writes its set
// bits' indices in ascending order. Reads 1 KB/row, writes K floats/row.
__global__ __launch_bounds__(128) void compact_idx(
    const unsigned long long* __restrict__ masks,
    float* __restrict__ out1)                    // indices as float32
{
    const int b    = blockIdx.x;
    const int tid  = threadIdx.x;   // 0..127
    const int lane = tid & 63;
    const int wave = tid >> 6;

    __shared__ unsigned int wsum[2];

    unsigned long long m = masks[b * (PN / 64) + tid];
    const unsigned int c = (unsigned int)__popcll(m);

    // Inclusive scan of counts within each wave (6 shfl_up steps).
    unsigned int inc = c;
#pragma unroll
    for (int d = 1; d < 64; d <<= 1) {
        unsigned int up = __shfl_up(inc, d, 64);
        if (lane >= d) inc += up;
    }
    if (lane == 63) wsum[wave] = inc;
    __syncthreads();

    // Exclusive prefix across the whole row (wave 1 adds wave 0's total).
    unsigned int pos = inc - c + (wave ? wsum[0] : 0u);

    // Emit indices of set bits, ascending n == stable argsort order.
    while (m) {
        const int bit = __builtin_ctzll(m);
        m &= m - 1;
        if (pos < PK)
            out1[b * PK + pos] = (float)(tid * 64 + bit);
        ++pos;
    }
}

extern "C" void kernel_launch(void* const* d_in, const int* in_sizes, int n_in,
                              void* d_out, int out_size, void* d_ws, size_t ws_size,
                              hipStream_t stream) {
    // Resolve inputs by size: the 1-element input is `id`, the big one is one_hot.
    const float* one_hot = nullptr;
    const int* id_ptr = nullptr;
    for (int i = 0; i < n_in; ++i) {
        if (in_sizes[i] == 1) id_ptr = (const int*)d_in[i];
        else                  one_hot = (const float*)d_in[i];
    }

    float* out0 = (float*)d_out;                    // B*N floats
    float* out1 = (float*)d_out + (size_t)PB * PN;  // B*K floats
    unsigned long long* masks = (unsigned long long*)d_ws;  // 32 KB, overwritten
                                                            // in full each iter
                                                            // before being read

    gather_col<<<dim3((PB * PN) / 256), dim3(256), 0, stream>>>(
        one_hot, id_ptr, out0, masks);
    compact_idx<<<dim3(PB), dim3(128), 0, stream>>>(masks, out1);
}